// Round 2
// baseline (608.538 us; speedup 1.0000x reference)
//
#include <hip/hip_runtime.h>
#include <math.h>

// Round 1 resubmission: rounds 0-1 never reached hardware (broker capacity /
// container failure). This is the fp32 correctness-first baseline; bf16
// split-MFMA for K8 is staged for after a green refcheck.

// Sizes
#define SEQ 64
#define EMB 128
#define TH 128          // per-direction hidden
#define G3 384          // 3*TH
#define KCNT 16384
#define KE 64
#define SH 512
#define GS3 1536        // 3*SH
#define INS 513         // 2*256+1

__device__ __forceinline__ float sigmoidf_(float x) {
    return 1.0f / (1.0f + expf(-x));
}

// ---------------------------------------------------------------------------
// K0: gi_all[dir][t][g] = dot(W_ih[g], emb[tok_t]) + b_ih[g]
// grid (64, 2), block 384
// ---------------------------------------------------------------------------
__global__ __launch_bounds__(384) void topic_gi_kernel(
    const int* __restrict__ topic, const float* __restrict__ emb,
    const float* __restrict__ Wih_f, const float* __restrict__ bih_f,
    const float* __restrict__ Wih_b, const float* __restrict__ bih_b,
    float* __restrict__ gi_ws)  // [2][64][384]
{
    const int t = blockIdx.x;
    const int dir = blockIdx.y;
    const int g = threadIdx.x;
    const float* Wih = dir ? Wih_b : Wih_f;
    const float* bih = dir ? bih_b : bih_f;
    const int tok = topic[dir ? (SEQ - 1 - t) : t];
    const float4* e4 = (const float4*)(emb + (size_t)tok * EMB);
    const float4* w4 = (const float4*)(Wih + (size_t)g * EMB);
    float acc = bih[g];
    #pragma unroll
    for (int q = 0; q < EMB / 4; ++q) {
        float4 w = w4[q], e = e4[q];
        acc += w.x * e.x + w.y * e.y + w.z * e.z + w.w * e.w;
    }
    gi_ws[((size_t)dir * SEQ + t) * G3 + g] = acc;
}

// ---------------------------------------------------------------------------
// K1: sequential GRU over 64 steps, one block per direction.
// W_hh row cached in registers; h in LDS; v = max over time of h states.
// grid 2, block 384
// ---------------------------------------------------------------------------
__global__ __launch_bounds__(384) void topic_gru_seq_kernel(
    const float* __restrict__ Whh_f, const float* __restrict__ bhh_f,
    const float* __restrict__ Whh_b, const float* __restrict__ bhh_b,
    const float* __restrict__ gi_ws, float* __restrict__ v_out)
{
    const int dir = blockIdx.x;
    const float* Whh = dir ? Whh_b : Whh_f;
    const float* bhh = dir ? bhh_b : bhh_f;
    const float* gi = gi_ws + (size_t)dir * SEQ * G3;
    const int tid = threadIdx.x;

    __shared__ float hbuf[TH];
    __shared__ float ghbuf[G3];

    // cache this thread's W_hh row (128 floats = 32 float4) in registers
    float4 w[32];
    const float4* w4 = (const float4*)(Whh + (size_t)tid * TH);
    #pragma unroll
    for (int q = 0; q < 32; ++q) w[q] = w4[q];
    const float bh = bhh[tid];

    if (tid < TH) hbuf[tid] = 0.0f;
    __syncthreads();

    float vmax = -1e30f;
    for (int t = 0; t < SEQ; ++t) {
        const float4* h4 = (const float4*)hbuf;
        float acc = bh;
        #pragma unroll
        for (int q = 0; q < 32; ++q) {
            float4 hh = h4[q];
            acc += w[q].x * hh.x + w[q].y * hh.y + w[q].z * hh.z + w[q].w * hh.w;
        }
        ghbuf[tid] = acc;
        __syncthreads();
        if (tid < TH) {
            float gir = gi[(size_t)t * G3 + tid];
            float giz = gi[(size_t)t * G3 + tid + TH];
            float gin = gi[(size_t)t * G3 + tid + 2 * TH];
            float r = sigmoidf_(gir + ghbuf[tid]);
            float z = sigmoidf_(giz + ghbuf[tid + TH]);
            float n = tanhf(fmaf(r, ghbuf[tid + 2 * TH], gin));
            float hn = (1.0f - z) * n + z * hbuf[tid];
            hbuf[tid] = hn;
            vmax = fmaxf(vmax, hn);
        }
        __syncthreads();
    }
    if (tid < TH) v_out[dir * TH + tid] = vmax;
}

// ---------------------------------------------------------------------------
// K2: kn[row] = dot(Wk[row,:16384], knowledge) + bk[row].  grid 64, block 256
// ---------------------------------------------------------------------------
__global__ __launch_bounds__(256) void kn_kernel(
    const float* __restrict__ Wk, const float* __restrict__ bk,
    const float* __restrict__ knowledge, float* __restrict__ kn)
{
    const int row = blockIdx.x;
    const int tid = threadIdx.x;
    const float4* w4 = (const float4*)(Wk + (size_t)row * KCNT);
    const float4* k4 = (const float4*)knowledge;
    float acc = 0.0f;
    for (int i = tid; i < KCNT / 4; i += 256) {
        float4 w = w4[i], k = k4[i];
        acc += w.x * k.x + w.y * k.y + w.z * k.z + w.w * k.w;
    }
    #pragma unroll
    for (int off = 32; off; off >>= 1) acc += __shfl_xor(acc, off);
    __shared__ float red[4];
    if ((tid & 63) == 0) red[tid >> 6] = acc;
    __syncthreads();
    if (tid == 0) kn[row] = red[0] + red[1] + red[2] + red[3] + bk[row];
}

// ---------------------------------------------------------------------------
// K3: alpha[row] = dot(km[row,:64], kn).  wave per row; grid 4096, block 256
// ---------------------------------------------------------------------------
__global__ __launch_bounds__(256) void alpha_kernel(
    const float* __restrict__ km, const float* __restrict__ kn,
    float* __restrict__ alpha)
{
    const int idx = blockIdx.x * 256 + threadIdx.x;
    const int row = idx >> 6;
    const int lane = idx & 63;
    float p = km[(size_t)row * KE + lane] * kn[lane];
    #pragma unroll
    for (int off = 32; off; off >>= 1) p += __shfl_xor(p, off);
    if (lane == 0) alpha[row] = p;
}

// ---------------------------------------------------------------------------
// K4: beta = softmax(alpha) over 16384.  1 block, 1024 threads, 16 elem/thread
// ---------------------------------------------------------------------------
__global__ __launch_bounds__(1024) void softmax_kernel(
    const float* __restrict__ alpha, float* __restrict__ beta)
{
    const int tid = threadIdx.x;
    float vals[16];
    float m = -1e30f;
    #pragma unroll
    for (int i = 0; i < 16; ++i) {
        vals[i] = alpha[tid + i * 1024];
        m = fmaxf(m, vals[i]);
    }
    #pragma unroll
    for (int off = 32; off; off >>= 1) m = fmaxf(m, __shfl_xor(m, off));
    __shared__ float red[16];
    if ((tid & 63) == 0) red[tid >> 6] = m;
    __syncthreads();
    float M = red[0];
    #pragma unroll
    for (int wv = 1; wv < 16; ++wv) M = fmaxf(M, red[wv]);
    __syncthreads();
    float s = 0.0f;
    #pragma unroll
    for (int i = 0; i < 16; ++i) {
        vals[i] = expf(vals[i] - M);
        s += vals[i];
    }
    #pragma unroll
    for (int off = 32; off; off >>= 1) s += __shfl_xor(s, off);
    if ((tid & 63) == 0) red[tid >> 6] = s;
    __syncthreads();
    float S = 0.0f;
    #pragma unroll
    for (int wv = 0; wv < 16; ++wv) S += red[wv];
    const float inv = 1.0f / S;
    #pragma unroll
    for (int i = 0; i < 16; ++i) beta[tid + i * 1024] = vals[i] * inv;
}

// ---------------------------------------------------------------------------
// K5: partial hkp: part[b][j] = sum_{r in block b} beta[r]*h[r][j]
// grid 128, block 512 (thread j owns column j)
// ---------------------------------------------------------------------------
__global__ __launch_bounds__(512) void hkp_partial_kernel(
    const float* __restrict__ beta, const float* __restrict__ hinit,
    float* __restrict__ part)
{
    const int j = threadIdx.x;
    const int b = blockIdx.x;
    const int r0 = b * (KCNT / 128);
    float acc = 0.0f;
    for (int r = 0; r < KCNT / 128; ++r)
        acc = fmaf(beta[r0 + r], hinit[(size_t)(r0 + r) * SH + j], acc);
    part[(size_t)b * SH + j] = acc;
}

// ---------------------------------------------------------------------------
// K6: reduce part -> hkp, predict_score -> out[0], build x_in[513]
// 1 block, 512 threads
// ---------------------------------------------------------------------------
__global__ __launch_bounds__(512) void score_xin_kernel(
    const float* __restrict__ part, const float* __restrict__ v,
    const float* __restrict__ score, const float* __restrict__ Ws,
    const float* __restrict__ bs, float* __restrict__ x_in,
    float* __restrict__ out)
{
    const int tid = threadIdx.x;
    float hkp = 0.0f;
    for (int b = 0; b < 128; ++b) hkp += part[(size_t)b * SH + tid];
    float contrib = hkp * Ws[256 + tid];
    if (tid < 256) contrib += v[tid] * Ws[tid];
    #pragma unroll
    for (int off = 32; off; off >>= 1) contrib += __shfl_xor(contrib, off);
    __shared__ float red[8];
    if ((tid & 63) == 0) red[tid >> 6] = contrib;
    __syncthreads();
    if (tid == 0) {
        float p = bs[0];
        #pragma unroll
        for (int wv = 0; wv < 8; ++wv) p += red[wv];
        out[0] = p;
    }
    const float sc = score[0];
    const float pos = (sc >= 0.5f) ? 1.0f : 0.0f;
    if (tid < 256) {
        x_in[tid] = v[tid] * pos;
        x_in[256 + tid] = v[tid] * (1.0f - pos);
    }
    if (tid == 0) x_in[512] = sc;
}

// ---------------------------------------------------------------------------
// K7: g_raw[g] = dot(W_ih_s[g,:513], x_in)   (NO bias -- added in epilogue)
// wave per row; grid 384, block 256
// ---------------------------------------------------------------------------
__global__ __launch_bounds__(256) void gih_kernel(
    const float* __restrict__ Wih_s, const float* __restrict__ x_in,
    float* __restrict__ g_raw)
{
    const int gw = (blockIdx.x * 256 + threadIdx.x) >> 6;
    const int lane = threadIdx.x & 63;
    const float* row = Wih_s + (size_t)gw * INS;
    float acc = 0.0f;
    for (int k = lane; k < INS; k += 64) acc += row[k] * x_in[k];
    #pragma unroll
    for (int off = 32; off; off >>= 1) acc += __shfl_xor(acc, off);
    if (lane == 0) g_raw[gw] = acc;
}

// ---------------------------------------------------------------------------
// K8: fused gh-GEMM + GRU cell.
// gh[i,:] = h[i,:] @ W_hh_s.T + b_hh;  gi[i,:] = beta[i]*g_raw + b_ih
// h_new[i,j] = (1-z)*n + z*h[i,j]
// Tiles: BM=64 rows x BN=64 cols (192 GEMM cols: r/z/n slices), BK=32.
// grid 2048 (= 256 row-tiles x 8 col-tiles, col fastest), block 256.
// ---------------------------------------------------------------------------
#define BM 64
#define BN 64
#define BK 32

__global__ __launch_bounds__(256) void slot_gru_kernel(
    const float* __restrict__ hinit,   // [16384,512]
    const float* __restrict__ Whh,     // [1536,512]
    const float* __restrict__ beta,    // [16384]
    const float* __restrict__ g_raw,   // [1536]
    const float* __restrict__ b_ih,    // [1536]
    const float* __restrict__ b_hh,    // [1536]
    float* __restrict__ out)           // out[0]=score, out+1 = h_new
{
    __shared__ float As[BK][BM];        // 8 KB  (k-major)
    __shared__ float Bs[BK][3 * BN];    // 24 KB

    const int tid = threadIdx.x;
    const int ct = blockIdx.x & 7;
    const int rt = blockIdx.x >> 3;
    const int m0 = rt * BM;
    const int c0 = ct * BN;
    const int tm = (tid & 15) * 4;      // micro-tile rows
    const int tc = (tid >> 4) * 4;      // micro-tile cols

    float acc[4][12];
    #pragma unroll
    for (int i = 0; i < 4; ++i)
        #pragma unroll
        for (int j = 0; j < 12; ++j) acc[i][j] = 0.0f;

    for (int k0 = 0; k0 < SH; k0 += BK) {
        // A tile: 64 rows x 32 k
        #pragma unroll
        for (int p = 0; p < 2; ++p) {
            const int m = (tid >> 3) + p * 32;
            const int kc = (tid & 7) * 4;
            const float4 a = *(const float4*)(hinit + (size_t)(m0 + m) * SH + k0 + kc);
            As[kc + 0][m] = a.x; As[kc + 1][m] = a.y;
            As[kc + 2][m] = a.z; As[kc + 3][m] = a.w;
        }
        // B tile: 192 rows (3 gate slices x 64 cols) x 32 k
        #pragma unroll
        for (int p = 0; p < 6; ++p) {
            const int r = (tid >> 3) + p * 32;
            const int kc = (tid & 7) * 4;
            const int slice = r >> 6;
            const int wrow = slice * SH + c0 + (r & 63);
            const float4 b = *(const float4*)(Whh + (size_t)wrow * SH + k0 + kc);
            Bs[kc + 0][r] = b.x; Bs[kc + 1][r] = b.y;
            Bs[kc + 2][r] = b.z; Bs[kc + 3][r] = b.w;
        }
        __syncthreads();

        for (int k = 0; k < BK; ++k) {
            const float4 av = *(const float4*)&As[k][tm];
            const float4 b0 = *(const float4*)&Bs[k][tc];
            const float4 b1 = *(const float4*)&Bs[k][BN + tc];
            const float4 b2 = *(const float4*)&Bs[k][2 * BN + tc];
            const float a[4] = {av.x, av.y, av.z, av.w};
            const float bb[12] = {b0.x, b0.y, b0.z, b0.w,
                                  b1.x, b1.y, b1.z, b1.w,
                                  b2.x, b2.y, b2.z, b2.w};
            #pragma unroll
            for (int i = 0; i < 4; ++i)
                #pragma unroll
                for (int j = 0; j < 12; ++j)
                    acc[i][j] = fmaf(a[i], bb[j], acc[i][j]);
        }
        __syncthreads();
    }

    // epilogue: gates + output (float4 stores, cols contiguous)
    #pragma unroll
    for (int i = 0; i < 4; ++i) {
        const int row = m0 + tm + i;
        const float b = beta[row];
        const float4 hp = *(const float4*)(hinit + (size_t)row * SH + c0 + tc);
        float o[4];
        const float hprev[4] = {hp.x, hp.y, hp.z, hp.w};
        #pragma unroll
        for (int j = 0; j < 4; ++j) {
            const int col = c0 + tc + j;
            const float ghr = acc[i][j] + b_hh[col];
            const float ghz = acc[i][4 + j] + b_hh[col + SH];
            const float ghn = acc[i][8 + j] + b_hh[col + 2 * SH];
            const float gir = fmaf(b, g_raw[col], b_ih[col]);
            const float giz = fmaf(b, g_raw[col + SH], b_ih[col + SH]);
            const float gin = fmaf(b, g_raw[col + 2 * SH], b_ih[col + 2 * SH]);
            const float r = sigmoidf_(gir + ghr);
            const float z = sigmoidf_(giz + ghz);
            const float n = tanhf(fmaf(r, ghn, gin));
            o[j] = (1.0f - z) * n + z * hprev[j];
        }
        *(float4*)(out + 1 + (size_t)row * SH + c0 + tc) =
            make_float4(o[0], o[1], o[2], o[3]);
    }
}

// ---------------------------------------------------------------------------
extern "C" void kernel_launch(void* const* d_in, const int* in_sizes, int n_in,
                              void* d_out, int out_size, void* d_ws, size_t ws_size,
                              hipStream_t stream) {
    const int*   topic     = (const int*)d_in[0];
    const float* knowledge = (const float*)d_in[1];
    const float* score     = (const float*)d_in[2];
    const float* emb       = (const float*)d_in[3];
    const float* Wih_f     = (const float*)d_in[4];
    const float* Whh_f     = (const float*)d_in[5];
    const float* bih_f     = (const float*)d_in[6];
    const float* bhh_f     = (const float*)d_in[7];
    const float* Wih_b     = (const float*)d_in[8];
    const float* Whh_b     = (const float*)d_in[9];
    const float* bih_b     = (const float*)d_in[10];
    const float* bhh_b     = (const float*)d_in[11];
    const float* Wk        = (const float*)d_in[12];
    const float* bk        = (const float*)d_in[13];
    const float* km        = (const float*)d_in[14];
    const float* h0        = (const float*)d_in[15];
    const float* Ws        = (const float*)d_in[16];
    const float* bs        = (const float*)d_in[17];
    const float* Wih_s     = (const float*)d_in[18];
    const float* Whh_s     = (const float*)d_in[19];
    const float* bih_s     = (const float*)d_in[20];
    const float* bhh_s     = (const float*)d_in[21];

    float* out = (float*)d_out;
    float* ws  = (float*)d_ws;

    // workspace layout (floats)
    float* v     = ws + 0;       // 256
    float* kn    = ws + 256;     // 64
    float* alpha = ws + 320;     // 16384
    float* beta  = ws + 16704;   // 16384
    float* part  = ws + 33088;   // 128*512 = 65536
    float* x_in  = ws + 98624;   // 513 (pad 516)
    float* g_raw = ws + 99140;   // 1536
    float* gi_ws = ws + 100680;  // 2*64*384 = 49152  (end ~149832 floats)

    topic_gi_kernel<<<dim3(SEQ, 2), G3, 0, stream>>>(topic, emb, Wih_f, bih_f,
                                                     Wih_b, bih_b, gi_ws);
    topic_gru_seq_kernel<<<2, G3, 0, stream>>>(Whh_f, bhh_f, Whh_b, bhh_b,
                                               gi_ws, v);
    kn_kernel<<<KE, 256, 0, stream>>>(Wk, bk, knowledge, kn);
    alpha_kernel<<<KCNT * 64 / 256, 256, 0, stream>>>(km, kn, alpha);
    softmax_kernel<<<1, 1024, 0, stream>>>(alpha, beta);
    hkp_partial_kernel<<<128, 512, 0, stream>>>(beta, h0, part);
    score_xin_kernel<<<1, 512, 0, stream>>>(part, v, score, Ws, bs, x_in, out);
    gih_kernel<<<GS3 / 4, 256, 0, stream>>>(Wih_s, x_in, g_raw);
    slot_gru_kernel<<<(KCNT / BM) * (SH / BN), 256, 0, stream>>>(
        h0, Whh_s, beta, g_raw, bih_s, bhh_s, out);
}

// Round 3
// 327.825 us; speedup vs baseline: 1.8563x; 1.8563x over previous
//
#include <hip/hip_runtime.h>
#include <math.h>

// Round 3: fp16-MFMA slot GRU (single MFMA, no split: fp16 rounding adds
// ~4e-4 to gh, ~10x below the baseline's measured absmax 0.0039 which comes
// from the reference's own matmul precision). Everything else unchanged.

// Sizes
#define SEQ 64
#define EMB 128
#define TH 128          // per-direction hidden
#define G3 384          // 3*TH
#define KCNT 16384
#define KE 64
#define SH 512
#define GS3 1536        // 3*SH
#define INS 513         // 2*256+1

typedef _Float16 f16x8 __attribute__((ext_vector_type(8)));
typedef float f32x4 __attribute__((ext_vector_type(4)));

__device__ __forceinline__ float sigmoidf_(float x) {
    return 1.0f / (1.0f + expf(-x));
}
__device__ __forceinline__ float sigmoid_fast(float x) {
    return 1.0f / (1.0f + __expf(-x));   // inf-safe: 1/(1+inf)=0
}
__device__ __forceinline__ float tanh_fast(float x) {
    return 2.0f / (1.0f + __expf(-2.0f * x)) - 1.0f;  // inf-safe at both ends
}

__device__ __forceinline__ void gl_lds16(const void* g, void* l) {
    __builtin_amdgcn_global_load_lds(
        (const __attribute__((address_space(1))) unsigned int*)g,
        (__attribute__((address_space(3))) unsigned int*)l, 16, 0, 0);
}

// ---------------------------------------------------------------------------
// K0: gi_all[dir][t][g] = dot(W_ih[g], emb[tok_t]) + b_ih[g]
// ---------------------------------------------------------------------------
__global__ __launch_bounds__(384) void topic_gi_kernel(
    const int* __restrict__ topic, const float* __restrict__ emb,
    const float* __restrict__ Wih_f, const float* __restrict__ bih_f,
    const float* __restrict__ Wih_b, const float* __restrict__ bih_b,
    float* __restrict__ gi_ws)  // [2][64][384]
{
    const int t = blockIdx.x;
    const int dir = blockIdx.y;
    const int g = threadIdx.x;
    const float* Wih = dir ? Wih_b : Wih_f;
    const float* bih = dir ? bih_b : bih_f;
    const int tok = topic[dir ? (SEQ - 1 - t) : t];
    const float4* e4 = (const float4*)(emb + (size_t)tok * EMB);
    const float4* w4 = (const float4*)(Wih + (size_t)g * EMB);
    float acc = bih[g];
    #pragma unroll
    for (int q = 0; q < EMB / 4; ++q) {
        float4 w = w4[q], e = e4[q];
        acc += w.x * e.x + w.y * e.y + w.z * e.z + w.w * e.w;
    }
    gi_ws[((size_t)dir * SEQ + t) * G3 + g] = acc;
}

// ---------------------------------------------------------------------------
// K1: sequential GRU over 64 steps, one block per direction.
// ---------------------------------------------------------------------------
__global__ __launch_bounds__(384) void topic_gru_seq_kernel(
    const float* __restrict__ Whh_f, const float* __restrict__ bhh_f,
    const float* __restrict__ Whh_b, const float* __restrict__ bhh_b,
    const float* __restrict__ gi_ws, float* __restrict__ v_out)
{
    const int dir = blockIdx.x;
    const float* Whh = dir ? Whh_b : Whh_f;
    const float* bhh = dir ? bhh_b : bhh_f;
    const float* gi = gi_ws + (size_t)dir * SEQ * G3;
    const int tid = threadIdx.x;

    __shared__ float hbuf[TH];
    __shared__ float ghbuf[G3];

    float4 w[32];
    const float4* w4 = (const float4*)(Whh + (size_t)tid * TH);
    #pragma unroll
    for (int q = 0; q < 32; ++q) w[q] = w4[q];
    const float bh = bhh[tid];

    if (tid < TH) hbuf[tid] = 0.0f;
    __syncthreads();

    float vmax = -1e30f;
    for (int t = 0; t < SEQ; ++t) {
        const float4* h4 = (const float4*)hbuf;
        float acc = bh;
        #pragma unroll
        for (int q = 0; q < 32; ++q) {
            float4 hh = h4[q];
            acc += w[q].x * hh.x + w[q].y * hh.y + w[q].z * hh.z + w[q].w * hh.w;
        }
        ghbuf[tid] = acc;
        __syncthreads();
        if (tid < TH) {
            float gir = gi[(size_t)t * G3 + tid];
            float giz = gi[(size_t)t * G3 + tid + TH];
            float gin = gi[(size_t)t * G3 + tid + 2 * TH];
            float r = sigmoidf_(gir + ghbuf[tid]);
            float z = sigmoidf_(giz + ghbuf[tid + TH]);
            float n = tanhf(fmaf(r, ghbuf[tid + 2 * TH], gin));
            float hn = (1.0f - z) * n + z * hbuf[tid];
            hbuf[tid] = hn;
            vmax = fmaxf(vmax, hn);
        }
        __syncthreads();
    }
    if (tid < TH) v_out[dir * TH + tid] = vmax;
}

// ---------------------------------------------------------------------------
// K2: kn[row] = dot(Wk[row,:16384], knowledge) + bk[row]
// ---------------------------------------------------------------------------
__global__ __launch_bounds__(256) void kn_kernel(
    const float* __restrict__ Wk, const float* __restrict__ bk,
    const float* __restrict__ knowledge, float* __restrict__ kn)
{
    const int row = blockIdx.x;
    const int tid = threadIdx.x;
    const float4* w4 = (const float4*)(Wk + (size_t)row * KCNT);
    const float4* k4 = (const float4*)knowledge;
    float acc = 0.0f;
    for (int i = tid; i < KCNT / 4; i += 256) {
        float4 w = w4[i], k = k4[i];
        acc += w.x * k.x + w.y * k.y + w.z * k.z + w.w * k.w;
    }
    #pragma unroll
    for (int off = 32; off; off >>= 1) acc += __shfl_xor(acc, off);
    __shared__ float red[4];
    if ((tid & 63) == 0) red[tid >> 6] = acc;
    __syncthreads();
    if (tid == 0) kn[row] = red[0] + red[1] + red[2] + red[3] + bk[row];
}

// ---------------------------------------------------------------------------
// K3: alpha[row] = dot(km[row,:64], kn)
// ---------------------------------------------------------------------------
__global__ __launch_bounds__(256) void alpha_kernel(
    const float* __restrict__ km, const float* __restrict__ kn,
    float* __restrict__ alpha)
{
    const int idx = blockIdx.x * 256 + threadIdx.x;
    const int row = idx >> 6;
    const int lane = idx & 63;
    float p = km[(size_t)row * KE + lane] * kn[lane];
    #pragma unroll
    for (int off = 32; off; off >>= 1) p += __shfl_xor(p, off);
    if (lane == 0) alpha[row] = p;
}

// ---------------------------------------------------------------------------
// K4: beta = softmax(alpha) over 16384
// ---------------------------------------------------------------------------
__global__ __launch_bounds__(1024) void softmax_kernel(
    const float* __restrict__ alpha, float* __restrict__ beta)
{
    const int tid = threadIdx.x;
    float vals[16];
    float m = -1e30f;
    #pragma unroll
    for (int i = 0; i < 16; ++i) {
        vals[i] = alpha[tid + i * 1024];
        m = fmaxf(m, vals[i]);
    }
    #pragma unroll
    for (int off = 32; off; off >>= 1) m = fmaxf(m, __shfl_xor(m, off));
    __shared__ float red[16];
    if ((tid & 63) == 0) red[tid >> 6] = m;
    __syncthreads();
    float M = red[0];
    #pragma unroll
    for (int wv = 1; wv < 16; ++wv) M = fmaxf(M, red[wv]);
    __syncthreads();
    float s = 0.0f;
    #pragma unroll
    for (int i = 0; i < 16; ++i) {
        vals[i] = expf(vals[i] - M);
        s += vals[i];
    }
    #pragma unroll
    for (int off = 32; off; off >>= 1) s += __shfl_xor(s, off);
    if ((tid & 63) == 0) red[tid >> 6] = s;
    __syncthreads();
    float S = 0.0f;
    #pragma unroll
    for (int wv = 0; wv < 16; ++wv) S += red[wv];
    const float inv = 1.0f / S;
    #pragma unroll
    for (int i = 0; i < 16; ++i) beta[tid + i * 1024] = vals[i] * inv;
}

// ---------------------------------------------------------------------------
// K5: partial hkp
// ---------------------------------------------------------------------------
__global__ __launch_bounds__(512) void hkp_partial_kernel(
    const float* __restrict__ beta, const float* __restrict__ hinit,
    float* __restrict__ part)
{
    const int j = threadIdx.x;
    const int b = blockIdx.x;
    const int r0 = b * (KCNT / 128);
    float acc = 0.0f;
    for (int r = 0; r < KCNT / 128; ++r)
        acc = fmaf(beta[r0 + r], hinit[(size_t)(r0 + r) * SH + j], acc);
    part[(size_t)b * SH + j] = acc;
}

// ---------------------------------------------------------------------------
// K6: reduce part -> hkp, predict_score -> out[0], build x_in[513]
// ---------------------------------------------------------------------------
__global__ __launch_bounds__(512) void score_xin_kernel(
    const float* __restrict__ part, const float* __restrict__ v,
    const float* __restrict__ score, const float* __restrict__ Ws,
    const float* __restrict__ bs, float* __restrict__ x_in,
    float* __restrict__ out)
{
    const int tid = threadIdx.x;
    float hkp = 0.0f;
    for (int b = 0; b < 128; ++b) hkp += part[(size_t)b * SH + tid];
    float contrib = hkp * Ws[256 + tid];
    if (tid < 256) contrib += v[tid] * Ws[tid];
    #pragma unroll
    for (int off = 32; off; off >>= 1) contrib += __shfl_xor(contrib, off);
    __shared__ float red[8];
    if ((tid & 63) == 0) red[tid >> 6] = contrib;
    __syncthreads();
    if (tid == 0) {
        float p = bs[0];
        #pragma unroll
        for (int wv = 0; wv < 8; ++wv) p += red[wv];
        out[0] = p;
    }
    const float sc = score[0];
    const float pos = (sc >= 0.5f) ? 1.0f : 0.0f;
    if (tid < 256) {
        x_in[tid] = v[tid] * pos;
        x_in[256 + tid] = v[tid] * (1.0f - pos);
    }
    if (tid == 0) x_in[512] = sc;
}

// ---------------------------------------------------------------------------
// K7: g_raw[g] = dot(W_ih_s[g,:513], x_in)
// ---------------------------------------------------------------------------
__global__ __launch_bounds__(256) void gih_kernel(
    const float* __restrict__ Wih_s, const float* __restrict__ x_in,
    float* __restrict__ g_raw)
{
    const int gw = (blockIdx.x * 256 + threadIdx.x) >> 6;
    const int lane = threadIdx.x & 63;
    const float* row = Wih_s + (size_t)gw * INS;
    float acc = 0.0f;
    for (int k = lane; k < INS; k += 64) acc += row[k] * x_in[k];
    #pragma unroll
    for (int off = 32; off; off >>= 1) acc += __shfl_xor(acc, off);
    if (lane == 0) g_raw[gw] = acc;
}

// ---------------------------------------------------------------------------
// K9: fp32 -> fp16 conversion, 8 elems/thread
// ---------------------------------------------------------------------------
__global__ __launch_bounds__(256) void cvt_f16_kernel(
    const float* __restrict__ s, _Float16* __restrict__ d, int n8)
{
    const int i = blockIdx.x * 256 + threadIdx.x;
    if (i >= n8) return;
    const float4* s4 = (const float4*)s + (size_t)i * 2;
    const float4 a = s4[0], b = s4[1];
    f16x8 o;
    o[0] = (_Float16)a.x; o[1] = (_Float16)a.y;
    o[2] = (_Float16)a.z; o[3] = (_Float16)a.w;
    o[4] = (_Float16)b.x; o[5] = (_Float16)b.y;
    o[6] = (_Float16)b.z; o[7] = (_Float16)b.w;
    *(f16x8*)(d + (size_t)i * 8) = o;
}

// ---------------------------------------------------------------------------
// K8-MFMA: gh = h @ Whh.T via fp16 MFMA, fused GRU epilogue.
// Block: 128 rows x 64 out-cols x 3 gates. 256 thr = 4 waves, each wave
// 64 rows x 32 cols x 3 gates = 24 mfma_f32_16x16x32_f16 per BK=32 step.
// LDS: As [128][32] f16 (8KB), Bs [192][32] f16 (12KB), linear layout,
// global_load_lds width-16 staging (m97 pattern; 64B rows are at the LDS
// 8-cy floor for the ds_read_b128 frag pattern, no swizzle needed).
// grid 1024 = 128 Mtiles x 8 Ntiles (N fastest).
// ---------------------------------------------------------------------------
__global__ __launch_bounds__(256, 2) void slot_gru_mfma_kernel(
    const float* __restrict__ h32,    // [16384,512] fp32 (hprev)
    const _Float16* __restrict__ h16, // [16384,512]
    const _Float16* __restrict__ W16, // [1536,512]
    const float* __restrict__ beta,   // [16384]
    const float* __restrict__ g_raw,  // [1536]
    const float* __restrict__ b_ih,   // [1536]
    const float* __restrict__ b_hh,   // [1536]
    float* __restrict__ out)          // out[0]=score, out+1 = h_new
{
    __shared__ _Float16 As[128 * 32];      // [row][k]
    __shared__ _Float16 Bs[192 * 32];      // [gate*64+col][k]

    const int tid = threadIdx.x;
    const int lane = tid & 63;
    const int wv  = tid >> 6;
    const int wm  = (wv >> 1) * 64;
    const int wn  = (wv & 1) * 32;
    const int nt  = blockIdx.x & 7;
    const int mt  = blockIdx.x >> 3;
    const int m0  = mt * 128;
    const int c0  = nt * 64;
    const int l15 = lane & 15;
    const int l4  = lane >> 4;

    f32x4 acc[4][3][2];
    #pragma unroll
    for (int mi = 0; mi < 4; ++mi)
        #pragma unroll
        for (int g = 0; g < 3; ++g)
            #pragma unroll
            for (int ni = 0; ni < 2; ++ni)
                acc[mi][g][ni] = (f32x4){0.f, 0.f, 0.f, 0.f};

    for (int k0 = 0; k0 < SH; k0 += 32) {
        // stage A: 128 rows x 32 halves = 512 x 16B chunks
        #pragma unroll
        for (int p = 0; p < 2; ++p) {
            const int idx = tid + p * 256;
            const int r = idx >> 2, c = idx & 3;
            gl_lds16(h16 + (size_t)(m0 + r) * SH + k0 + c * 8, &As[idx * 8]);
        }
        // stage B: 192 rows (3 gates x 64 cols) x 32 halves = 768 chunks
        #pragma unroll
        for (int p = 0; p < 3; ++p) {
            const int idx = tid + p * 256;
            const int r = idx >> 2, c = idx & 3;
            const int g = r >> 6, wcol = r & 63;
            gl_lds16(W16 + (size_t)(g * SH + c0 + wcol) * SH + k0 + c * 8,
                     &Bs[idx * 8]);
        }
        __syncthreads();

        f16x8 af[4], bf[3][2];
        #pragma unroll
        for (int mi = 0; mi < 4; ++mi)
            af[mi] = *(const f16x8*)&As[(wm + mi * 16 + l15) * 32 + l4 * 8];
        #pragma unroll
        for (int g = 0; g < 3; ++g)
            #pragma unroll
            for (int ni = 0; ni < 2; ++ni)
                bf[g][ni] = *(const f16x8*)&Bs[(g * 64 + wn + ni * 16 + l15) * 32 + l4 * 8];

        #pragma unroll
        for (int mi = 0; mi < 4; ++mi)
            #pragma unroll
            for (int g = 0; g < 3; ++g)
                #pragma unroll
                for (int ni = 0; ni < 2; ++ni)
                    acc[mi][g][ni] = __builtin_amdgcn_mfma_f32_16x16x32_f16(
                        af[mi], bf[g][ni], acc[mi][g][ni], 0, 0, 0);
        __syncthreads();
    }

    // epilogue: per-col params (2 cols/thread)
    float bhh_[3][2], bih_[3][2], gr_[3][2];
    #pragma unroll
    for (int ni = 0; ni < 2; ++ni) {
        const int col = c0 + wn + ni * 16 + l15;
        #pragma unroll
        for (int g = 0; g < 3; ++g) {
            bhh_[g][ni] = b_hh[col + g * SH];
            bih_[g][ni] = b_ih[col + g * SH];
            gr_[g][ni]  = g_raw[col + g * SH];
        }
    }
    #pragma unroll
    for (int mi = 0; mi < 4; ++mi) {
        #pragma unroll
        for (int j = 0; j < 4; ++j) {
            const int row = m0 + wm + mi * 16 + l4 * 4 + j;
            const float bt = beta[row];
            #pragma unroll
            for (int ni = 0; ni < 2; ++ni) {
                const int col = c0 + wn + ni * 16 + l15;
                const float hp = h32[(size_t)row * SH + col];
                const float ghr = acc[mi][0][ni][j] + bhh_[0][ni];
                const float ghz = acc[mi][1][ni][j] + bhh_[1][ni];
                const float ghn = acc[mi][2][ni][j] + bhh_[2][ni];
                const float gir = fmaf(bt, gr_[0][ni], bih_[0][ni]);
                const float giz = fmaf(bt, gr_[1][ni], bih_[1][ni]);
                const float gin = fmaf(bt, gr_[2][ni], bih_[2][ni]);
                const float r = sigmoid_fast(gir + ghr);
                const float z = sigmoid_fast(giz + ghz);
                const float n = tanh_fast(fmaf(r, ghn, gin));
                out[1 + (size_t)row * SH + col] = (1.0f - z) * n + z * hp;
            }
        }
    }
}

// ---------------------------------------------------------------------------
// K8 fallback: fp32 tiled version (validated round 2) if ws too small.
// ---------------------------------------------------------------------------
#define BM 64
#define BN 64
#define BK 32

__global__ __launch_bounds__(256) void slot_gru_kernel(
    const float* __restrict__ hinit, const float* __restrict__ Whh,
    const float* __restrict__ beta, const float* __restrict__ g_raw,
    const float* __restrict__ b_ih, const float* __restrict__ b_hh,
    float* __restrict__ out)
{
    __shared__ float As_[BK][BM];
    __shared__ float Bs_[BK][3 * BN];

    const int tid = threadIdx.x;
    const int ct = blockIdx.x & 7;
    const int rt = blockIdx.x >> 3;
    const int m0 = rt * BM;
    const int c0 = ct * BN;
    const int tm = (tid & 15) * 4;
    const int tc = (tid >> 4) * 4;

    float acc[4][12];
    #pragma unroll
    for (int i = 0; i < 4; ++i)
        #pragma unroll
        for (int j = 0; j < 12; ++j) acc[i][j] = 0.0f;

    for (int k0 = 0; k0 < SH; k0 += BK) {
        #pragma unroll
        for (int p = 0; p < 2; ++p) {
            const int m = (tid >> 3) + p * 32;
            const int kc = (tid & 7) * 4;
            const float4 a = *(const float4*)(hinit + (size_t)(m0 + m) * SH + k0 + kc);
            As_[kc + 0][m] = a.x; As_[kc + 1][m] = a.y;
            As_[kc + 2][m] = a.z; As_[kc + 3][m] = a.w;
        }
        #pragma unroll
        for (int p = 0; p < 6; ++p) {
            const int r = (tid >> 3) + p * 32;
            const int kc = (tid & 7) * 4;
            const int slice = r >> 6;
            const int wrow = slice * SH + c0 + (r & 63);
            const float4 b = *(const float4*)(Whh + (size_t)wrow * SH + k0 + kc);
            Bs_[kc + 0][r] = b.x; Bs_[kc + 1][r] = b.y;
            Bs_[kc + 2][r] = b.z; Bs_[kc + 3][r] = b.w;
        }
        __syncthreads();
        for (int k = 0; k < BK; ++k) {
            const float4 av = *(const float4*)&As_[k][tm];
            const float4 b0 = *(const float4*)&Bs_[k][tc];
            const float4 b1 = *(const float4*)&Bs_[k][BN + tc];
            const float4 b2 = *(const float4*)&Bs_[k][2 * BN + tc];
            const float a[4] = {av.x, av.y, av.z, av.w};
            const float bb[12] = {b0.x, b0.y, b0.z, b0.w,
                                  b1.x, b1.y, b1.z, b1.w,
                                  b2.x, b2.y, b2.z, b2.w};
            #pragma unroll
            for (int i = 0; i < 4; ++i)
                #pragma unroll
                for (int j = 0; j < 12; ++j)
                    acc[i][j] = fmaf(a[i], bb[j], acc[i][j]);
        }
        __syncthreads();
    }
    #pragma unroll
    for (int i = 0; i < 4; ++i) {
        const int row = m0 + tm + i;
        const float b = beta[row];
        const float4 hp = *(const float4*)(hinit + (size_t)row * SH + c0 + tc);
        float o[4];
        const float hprev[4] = {hp.x, hp.y, hp.z, hp.w};
        #pragma unroll
        for (int j = 0; j < 4; ++j) {
            const int col = c0 + tc + j;
            const float ghr = acc[i][j] + b_hh[col];
            const float ghz = acc[i][4 + j] + b_hh[col + SH];
            const float ghn = acc[i][8 + j] + b_hh[col + 2 * SH];
            const float gir = fmaf(b, g_raw[col], b_ih[col]);
            const float giz = fmaf(b, g_raw[col + SH], b_ih[col + SH]);
            const float gin = fmaf(b, g_raw[col + 2 * SH], b_ih[col + 2 * SH]);
            const float r = sigmoidf_(gir + ghr);
            const float z = sigmoidf_(giz + ghz);
            const float n = tanhf(fmaf(r, ghn, gin));
            o[j] = (1.0f - z) * n + z * hprev[j];
        }
        *(float4*)(out + 1 + (size_t)row * SH + c0 + tc) =
            make_float4(o[0], o[1], o[2], o[3]);
    }
}

// ---------------------------------------------------------------------------
extern "C" void kernel_launch(void* const* d_in, const int* in_sizes, int n_in,
                              void* d_out, int out_size, void* d_ws, size_t ws_size,
                              hipStream_t stream) {
    const int*   topic     = (const int*)d_in[0];
    const float* knowledge = (const float*)d_in[1];
    const float* score     = (const float*)d_in[2];
    const float* emb       = (const float*)d_in[3];
    const float* Wih_f     = (const float*)d_in[4];
    const float* Whh_f     = (const float*)d_in[5];
    const float* bih_f     = (const float*)d_in[6];
    const float* bhh_f     = (const float*)d_in[7];
    const float* Wih_b     = (const float*)d_in[8];
    const float* Whh_b     = (const float*)d_in[9];
    const float* bih_b     = (const float*)d_in[10];
    const float* bhh_b     = (const float*)d_in[11];
    const float* Wk        = (const float*)d_in[12];
    const float* bk        = (const float*)d_in[13];
    const float* km        = (const float*)d_in[14];
    const float* h0        = (const float*)d_in[15];
    const float* Ws        = (const float*)d_in[16];
    const float* bs        = (const float*)d_in[17];
    const float* Wih_s     = (const float*)d_in[18];
    const float* Whh_s     = (const float*)d_in[19];
    const float* bih_s     = (const float*)d_in[20];
    const float* bhh_s     = (const float*)d_in[21];

    float* out = (float*)d_out;
    float* ws  = (float*)d_ws;

    // workspace layout (floats)
    float* v     = ws + 0;       // 256
    float* kn    = ws + 256;     // 64
    float* alpha = ws + 320;     // 16384
    float* beta  = ws + 16704;   // 16384
    float* part  = ws + 33088;   // 128*512
    float* x_in  = ws + 98624;   // 513 (pad 516)
    float* g_raw = ws + 99140;   // 1536
    float* gi_ws = ws + 100680;  // 2*64*384 (ends ~599KB)

    // fp16 region (16B-aligned)
    const size_t H16_OFF = 655360;                       // 640 KB
    const size_t W16_OFF = H16_OFF + (size_t)KCNT * SH * 2;  // +16 MB
    const size_t NEED    = W16_OFF + (size_t)GS3 * SH * 2;   // +1.5 MB
    _Float16* h16 = (_Float16*)((char*)d_ws + H16_OFF);
    _Float16* W16 = (_Float16*)((char*)d_ws + W16_OFF);
    const bool use_mfma = ws_size >= NEED;

    if (use_mfma) {
        cvt_f16_kernel<<<(KCNT * SH / 8 + 255) / 256, 256, 0, stream>>>(
            h0, h16, KCNT * SH / 8);
        cvt_f16_kernel<<<(GS3 * SH / 8 + 255) / 256, 256, 0, stream>>>(
            Whh_s, W16, GS3 * SH / 8);
    }

    topic_gi_kernel<<<dim3(SEQ, 2), G3, 0, stream>>>(topic, emb, Wih_f, bih_f,
                                                     Wih_b, bih_b, gi_ws);
    topic_gru_seq_kernel<<<2, G3, 0, stream>>>(Whh_f, bhh_f, Whh_b, bhh_b,
                                               gi_ws, v);
    kn_kernel<<<KE, 256, 0, stream>>>(Wk, bk, knowledge, kn);
    alpha_kernel<<<KCNT * 64 / 256, 256, 0, stream>>>(km, kn, alpha);
    softmax_kernel<<<1, 1024, 0, stream>>>(alpha, beta);
    hkp_partial_kernel<<<128, 512, 0, stream>>>(beta, h0, part);
    score_xin_kernel<<<1, 512, 0, stream>>>(part, v, score, Ws, bs, x_in, out);
    gih_kernel<<<GS3 / 4, 256, 0, stream>>>(Wih_s, x_in, g_raw);

    if (use_mfma) {
        slot_gru_mfma_kernel<<<(KCNT / 128) * (SH / 64), 256, 0, stream>>>(
            h0, h16, W16, beta, g_raw, bih_s, bhh_s, out);
    } else {
        slot_gru_kernel<<<(KCNT / BM) * (SH / BN), 256, 0, stream>>>(
            h0, Whh_s, beta, g_raw, bih_s, bhh_s, out);
    }
}

// Round 4
// 294.977 us; speedup vs baseline: 2.0630x; 1.1114x over previous
//
#include <hip/hip_runtime.h>
#include <math.h>

// Round 4: rewrite topic_gru_seq (93.5us, top dispatch, VGPR=80 proved the
// W register cache was dropped -> W re-streamed from cache every step).
// New: 512 thr, thread (j,s)=row x k-quarter, 96 VGPR static W cache,
// quad shfl reduce, 1 barrier/step (double-buffered h), gi in LDS.
// Also hkp_partial reads h16 (halves its traffic).

// Sizes
#define SEQ 64
#define EMB 128
#define TH 128          // per-direction hidden
#define G3 384          // 3*TH
#define KCNT 16384
#define KE 64
#define SH 512
#define GS3 1536        // 3*SH
#define INS 513         // 2*256+1

typedef _Float16 f16x8 __attribute__((ext_vector_type(8)));
typedef float f32x4 __attribute__((ext_vector_type(4)));

__device__ __forceinline__ float sigmoidf_(float x) {
    return 1.0f / (1.0f + expf(-x));
}
__device__ __forceinline__ float sigmoid_fast(float x) {
    return 1.0f / (1.0f + __expf(-x));   // inf-safe
}
__device__ __forceinline__ float tanh_fast(float x) {
    return 2.0f / (1.0f + __expf(-2.0f * x)) - 1.0f;  // inf-safe
}

__device__ __forceinline__ void gl_lds16(const void* g, void* l) {
    __builtin_amdgcn_global_load_lds(
        (const __attribute__((address_space(1))) unsigned int*)g,
        (__attribute__((address_space(3))) unsigned int*)l, 16, 0, 0);
}

// ---------------------------------------------------------------------------
// K0: gi_all[dir][t][g] = dot(W_ih[g], emb[tok_t]) + b_ih[g]
// ---------------------------------------------------------------------------
__global__ __launch_bounds__(384) void topic_gi_kernel(
    const int* __restrict__ topic, const float* __restrict__ emb,
    const float* __restrict__ Wih_f, const float* __restrict__ bih_f,
    const float* __restrict__ Wih_b, const float* __restrict__ bih_b,
    float* __restrict__ gi_ws)  // [2][64][384]
{
    const int t = blockIdx.x;
    const int dir = blockIdx.y;
    const int g = threadIdx.x;
    const float* Wih = dir ? Wih_b : Wih_f;
    const float* bih = dir ? bih_b : bih_f;
    const int tok = topic[dir ? (SEQ - 1 - t) : t];
    const float4* e4 = (const float4*)(emb + (size_t)tok * EMB);
    const float4* w4 = (const float4*)(Wih + (size_t)g * EMB);
    float acc = bih[g];
    #pragma unroll
    for (int q = 0; q < EMB / 4; ++q) {
        float4 w = w4[q], e = e4[q];
        acc += w.x * e.x + w.y * e.y + w.z * e.z + w.w * e.w;
    }
    gi_ws[((size_t)dir * SEQ + t) * G3 + g] = acc;
}

// ---------------------------------------------------------------------------
// K1: sequential topic GRU, 1 block/direction, 512 threads.
// thread (j = tid>>2, s = tid&3): owns output row j, k-slice [s*32, s*32+32).
// W rows (r,z,n gates) for the slice live in 24 float4 registers.
// gi preloaded to LDS; h double-buffered in LDS; ONE barrier per step.
// ---------------------------------------------------------------------------
__global__ __launch_bounds__(512) void topic_gru_seq_kernel(
    const float* __restrict__ Whh_f, const float* __restrict__ bhh_f,
    const float* __restrict__ Whh_b, const float* __restrict__ bhh_b,
    const float* __restrict__ gi_ws, float* __restrict__ v_out)
{
    const int dir = blockIdx.x;
    const float* __restrict__ Whh = dir ? Whh_b : Whh_f;
    const float* __restrict__ bhh = dir ? bhh_b : bhh_f;
    const float* __restrict__ gi = gi_ws + (size_t)dir * SEQ * G3;
    const int tid = threadIdx.x;
    const int j = tid >> 2;
    const int s = tid & 3;

    __shared__ float gi_lds[SEQ * G3];   // 96 KB
    __shared__ float hls[2][TH];         // 1 KB double-buffered h

    // preload gi (24576 floats, 12 float4/thread, coalesced)
    {
        const float4* src = (const float4*)gi;
        float4* dst = (float4*)gi_lds;
        #pragma unroll
        for (int i = 0; i < SEQ * G3 / 4 / 512; ++i)
            dst[tid + i * 512] = src[tid + i * 512];
    }

    // W slice in registers: gate rows j, j+128, j+256; cols [s*32, s*32+32)
    float4 wr[8], wz[8], wn[8];
    {
        const float4* pr = (const float4*)(Whh + (size_t)j * TH + s * 32);
        const float4* pz = (const float4*)(Whh + (size_t)(TH + j) * TH + s * 32);
        const float4* pn = (const float4*)(Whh + (size_t)(2 * TH + j) * TH + s * 32);
        #pragma unroll
        for (int q = 0; q < 8; ++q) { wr[q] = pr[q]; wz[q] = pz[q]; wn[q] = pn[q]; }
    }
    const float bhr = bhh[j], bhz = bhh[j + TH], bhn = bhh[j + 2 * TH];

    if (tid < TH) hls[0][tid] = 0.0f;
    float h_old = 0.0f, vmax = -1e30f;
    __syncthreads();

    int cur = 0;
    for (int t = 0; t < SEQ; ++t) {
        const float4* h4 = (const float4*)(&hls[cur][s * 32]);
        float ar0 = 0.f, ar1 = 0.f, az0 = 0.f, az1 = 0.f, an0 = 0.f, an1 = 0.f;
        #pragma unroll
        for (int q = 0; q < 8; q += 2) {
            const float4 h0v = h4[q], h1v = h4[q + 1];
            ar0 = fmaf(wr[q].x, h0v.x, ar0); ar0 = fmaf(wr[q].y, h0v.y, ar0);
            ar0 = fmaf(wr[q].z, h0v.z, ar0); ar0 = fmaf(wr[q].w, h0v.w, ar0);
            ar1 = fmaf(wr[q+1].x, h1v.x, ar1); ar1 = fmaf(wr[q+1].y, h1v.y, ar1);
            ar1 = fmaf(wr[q+1].z, h1v.z, ar1); ar1 = fmaf(wr[q+1].w, h1v.w, ar1);
            az0 = fmaf(wz[q].x, h0v.x, az0); az0 = fmaf(wz[q].y, h0v.y, az0);
            az0 = fmaf(wz[q].z, h0v.z, az0); az0 = fmaf(wz[q].w, h0v.w, az0);
            az1 = fmaf(wz[q+1].x, h1v.x, az1); az1 = fmaf(wz[q+1].y, h1v.y, az1);
            az1 = fmaf(wz[q+1].z, h1v.z, az1); az1 = fmaf(wz[q+1].w, h1v.w, az1);
            an0 = fmaf(wn[q].x, h0v.x, an0); an0 = fmaf(wn[q].y, h0v.y, an0);
            an0 = fmaf(wn[q].z, h0v.z, an0); an0 = fmaf(wn[q].w, h0v.w, an0);
            an1 = fmaf(wn[q+1].x, h1v.x, an1); an1 = fmaf(wn[q+1].y, h1v.y, an1);
            an1 = fmaf(wn[q+1].z, h1v.z, an1); an1 = fmaf(wn[q+1].w, h1v.w, an1);
        }
        float ar = ar0 + ar1, az = az0 + az1, an = an0 + an1;
        ar += __shfl_xor(ar, 1); ar += __shfl_xor(ar, 2);
        az += __shfl_xor(az, 1); az += __shfl_xor(az, 2);
        an += __shfl_xor(an, 1); an += __shfl_xor(an, 2);
        if (s == 0) {
            const float gir = gi_lds[t * G3 + j];
            const float giz = gi_lds[t * G3 + j + TH];
            const float gin = gi_lds[t * G3 + j + 2 * TH];
            const float r = sigmoidf_(gir + ar + bhr);
            const float z = sigmoidf_(giz + az + bhz);
            const float n = tanhf(fmaf(r, an + bhn, gin));
            const float hn = (1.0f - z) * n + z * h_old;
            hls[cur ^ 1][j] = hn;
            h_old = hn;
            vmax = fmaxf(vmax, hn);
        }
        __syncthreads();
        cur ^= 1;
    }
    if (s == 0) v_out[dir * TH + j] = vmax;
}

// ---------------------------------------------------------------------------
// K2: kn[row] = dot(Wk[row,:16384], knowledge) + bk[row]
// ---------------------------------------------------------------------------
__global__ __launch_bounds__(256) void kn_kernel(
    const float* __restrict__ Wk, const float* __restrict__ bk,
    const float* __restrict__ knowledge, float* __restrict__ kn)
{
    const int row = blockIdx.x;
    const int tid = threadIdx.x;
    const float4* w4 = (const float4*)(Wk + (size_t)row * KCNT);
    const float4* k4 = (const float4*)knowledge;
    float acc = 0.0f;
    for (int i = tid; i < KCNT / 4; i += 256) {
        float4 w = w4[i], k = k4[i];
        acc += w.x * k.x + w.y * k.y + w.z * k.z + w.w * k.w;
    }
    #pragma unroll
    for (int off = 32; off; off >>= 1) acc += __shfl_xor(acc, off);
    __shared__ float red[4];
    if ((tid & 63) == 0) red[tid >> 6] = acc;
    __syncthreads();
    if (tid == 0) kn[row] = red[0] + red[1] + red[2] + red[3] + bk[row];
}

// ---------------------------------------------------------------------------
// K3: alpha[row] = dot(km[row,:64], kn)
// ---------------------------------------------------------------------------
__global__ __launch_bounds__(256) void alpha_kernel(
    const float* __restrict__ km, const float* __restrict__ kn,
    float* __restrict__ alpha)
{
    const int idx = blockIdx.x * 256 + threadIdx.x;
    const int row = idx >> 6;
    const int lane = idx & 63;
    float p = km[(size_t)row * KE + lane] * kn[lane];
    #pragma unroll
    for (int off = 32; off; off >>= 1) p += __shfl_xor(p, off);
    if (lane == 0) alpha[row] = p;
}

// ---------------------------------------------------------------------------
// K4: beta = softmax(alpha) over 16384
// ---------------------------------------------------------------------------
__global__ __launch_bounds__(1024) void softmax_kernel(
    const float* __restrict__ alpha, float* __restrict__ beta)
{
    const int tid = threadIdx.x;
    float vals[16];
    float m = -1e30f;
    #pragma unroll
    for (int i = 0; i < 16; ++i) {
        vals[i] = alpha[tid + i * 1024];
        m = fmaxf(m, vals[i]);
    }
    #pragma unroll
    for (int off = 32; off; off >>= 1) m = fmaxf(m, __shfl_xor(m, off));
    __shared__ float red[16];
    if ((tid & 63) == 0) red[tid >> 6] = m;
    __syncthreads();
    float M = red[0];
    #pragma unroll
    for (int wv = 1; wv < 16; ++wv) M = fmaxf(M, red[wv]);
    __syncthreads();
    float s = 0.0f;
    #pragma unroll
    for (int i = 0; i < 16; ++i) {
        vals[i] = expf(vals[i] - M);
        s += vals[i];
    }
    #pragma unroll
    for (int off = 32; off; off >>= 1) s += __shfl_xor(s, off);
    if ((tid & 63) == 0) red[tid >> 6] = s;
    __syncthreads();
    float S = 0.0f;
    #pragma unroll
    for (int wv = 0; wv < 16; ++wv) S += red[wv];
    const float inv = 1.0f / S;
    #pragma unroll
    for (int i = 0; i < 16; ++i) beta[tid + i * 1024] = vals[i] * inv;
}

// ---------------------------------------------------------------------------
// K5: partial hkp (reads fp16 h -> half the traffic; feeds only the scalar
// predict_score, fp16 rounding ~5e-4 on it, well under measured 0.0039 slack)
// ---------------------------------------------------------------------------
__global__ __launch_bounds__(512) void hkp_partial_kernel(
    const float* __restrict__ beta, const _Float16* __restrict__ h16,
    float* __restrict__ part)
{
    const int j = threadIdx.x;
    const int b = blockIdx.x;
    const int r0 = b * (KCNT / 128);
    float acc = 0.0f;
    for (int r = 0; r < KCNT / 128; ++r)
        acc = fmaf(beta[r0 + r], (float)h16[(size_t)(r0 + r) * SH + j], acc);
    part[(size_t)b * SH + j] = acc;
}

// ---------------------------------------------------------------------------
// K6: reduce part -> hkp, predict_score -> out[0], build x_in[513]
// ---------------------------------------------------------------------------
__global__ __launch_bounds__(512) void score_xin_kernel(
    const float* __restrict__ part, const float* __restrict__ v,
    const float* __restrict__ score, const float* __restrict__ Ws,
    const float* __restrict__ bs, float* __restrict__ x_in,
    float* __restrict__ out)
{
    const int tid = threadIdx.x;
    float hkp = 0.0f;
    for (int b = 0; b < 128; ++b) hkp += part[(size_t)b * SH + tid];
    float contrib = hkp * Ws[256 + tid];
    if (tid < 256) contrib += v[tid] * Ws[tid];
    #pragma unroll
    for (int off = 32; off; off >>= 1) contrib += __shfl_xor(contrib, off);
    __shared__ float red[8];
    if ((tid & 63) == 0) red[tid >> 6] = contrib;
    __syncthreads();
    if (tid == 0) {
        float p = bs[0];
        #pragma unroll
        for (int wv = 0; wv < 8; ++wv) p += red[wv];
        out[0] = p;
    }
    const float sc = score[0];
    const float pos = (sc >= 0.5f) ? 1.0f : 0.0f;
    if (tid < 256) {
        x_in[tid] = v[tid] * pos;
        x_in[256 + tid] = v[tid] * (1.0f - pos);
    }
    if (tid == 0) x_in[512] = sc;
}

// ---------------------------------------------------------------------------
// K7: g_raw[g] = dot(W_ih_s[g,:513], x_in)
// ---------------------------------------------------------------------------
__global__ __launch_bounds__(256) void gih_kernel(
    const float* __restrict__ Wih_s, const float* __restrict__ x_in,
    float* __restrict__ g_raw)
{
    const int gw = (blockIdx.x * 256 + threadIdx.x) >> 6;
    const int lane = threadIdx.x & 63;
    const float* row = Wih_s + (size_t)gw * INS;
    float acc = 0.0f;
    for (int k = lane; k < INS; k += 64) acc += row[k] * x_in[k];
    #pragma unroll
    for (int off = 32; off; off >>= 1) acc += __shfl_xor(acc, off);
    if (lane == 0) g_raw[gw] = acc;
}

// ---------------------------------------------------------------------------
// K9: fp32 -> fp16 conversion, 8 elems/thread
// ---------------------------------------------------------------------------
__global__ __launch_bounds__(256) void cvt_f16_kernel(
    const float* __restrict__ s, _Float16* __restrict__ d, int n8)
{
    const int i = blockIdx.x * 256 + threadIdx.x;
    if (i >= n8) return;
    const float4* s4 = (const float4*)s + (size_t)i * 2;
    const float4 a = s4[0], b = s4[1];
    f16x8 o;
    o[0] = (_Float16)a.x; o[1] = (_Float16)a.y;
    o[2] = (_Float16)a.z; o[3] = (_Float16)a.w;
    o[4] = (_Float16)b.x; o[5] = (_Float16)b.y;
    o[6] = (_Float16)b.z; o[7] = (_Float16)b.w;
    *(f16x8*)(d + (size_t)i * 8) = o;
}

// ---------------------------------------------------------------------------
// K8-MFMA: gh = h @ Whh.T via fp16 MFMA, fused GRU epilogue.
// (validated round 3: total kernel chain passed, absmax unchanged)
// ---------------------------------------------------------------------------
__global__ __launch_bounds__(256, 2) void slot_gru_mfma_kernel(
    const float* __restrict__ h32,    // [16384,512] fp32 (hprev)
    const _Float16* __restrict__ h16, // [16384,512]
    const _Float16* __restrict__ W16, // [1536,512]
    const float* __restrict__ beta,   // [16384]
    const float* __restrict__ g_raw,  // [1536]
    const float* __restrict__ b_ih,   // [1536]
    const float* __restrict__ b_hh,   // [1536]
    float* __restrict__ out)          // out[0]=score, out+1 = h_new
{
    __shared__ _Float16 As[128 * 32];      // [row][k]
    __shared__ _Float16 Bs[192 * 32];      // [gate*64+col][k]

    const int tid = threadIdx.x;
    const int lane = tid & 63;
    const int wv  = tid >> 6;
    const int wm  = (wv >> 1) * 64;
    const int wn  = (wv & 1) * 32;
    const int nt  = blockIdx.x & 7;
    const int mt  = blockIdx.x >> 3;
    const int m0  = mt * 128;
    const int c0  = nt * 64;
    const int l15 = lane & 15;
    const int l4  = lane >> 4;

    f32x4 acc[4][3][2];
    #pragma unroll
    for (int mi = 0; mi < 4; ++mi)
        #pragma unroll
        for (int g = 0; g < 3; ++g)
            #pragma unroll
            for (int ni = 0; ni < 2; ++ni)
                acc[mi][g][ni] = (f32x4){0.f, 0.f, 0.f, 0.f};

    for (int k0 = 0; k0 < SH; k0 += 32) {
        #pragma unroll
        for (int p = 0; p < 2; ++p) {
            const int idx = tid + p * 256;
            const int r = idx >> 2, c = idx & 3;
            gl_lds16(h16 + (size_t)(m0 + r) * SH + k0 + c * 8, &As[idx * 8]);
        }
        #pragma unroll
        for (int p = 0; p < 3; ++p) {
            const int idx = tid + p * 256;
            const int r = idx >> 2, c = idx & 3;
            const int g = r >> 6, wcol = r & 63;
            gl_lds16(W16 + (size_t)(g * SH + c0 + wcol) * SH + k0 + c * 8,
                     &Bs[idx * 8]);
        }
        __syncthreads();

        f16x8 af[4], bf[3][2];
        #pragma unroll
        for (int mi = 0; mi < 4; ++mi)
            af[mi] = *(const f16x8*)&As[(wm + mi * 16 + l15) * 32 + l4 * 8];
        #pragma unroll
        for (int g = 0; g < 3; ++g)
            #pragma unroll
            for (int ni = 0; ni < 2; ++ni)
                bf[g][ni] = *(const f16x8*)&Bs[(g * 64 + wn + ni * 16 + l15) * 32 + l4 * 8];

        #pragma unroll
        for (int mi = 0; mi < 4; ++mi)
            #pragma unroll
            for (int g = 0; g < 3; ++g)
                #pragma unroll
                for (int ni = 0; ni < 2; ++ni)
                    acc[mi][g][ni] = __builtin_amdgcn_mfma_f32_16x16x32_f16(
                        af[mi], bf[g][ni], acc[mi][g][ni], 0, 0, 0);
        __syncthreads();
    }

    float bhh_[3][2], bih_[3][2], gr_[3][2];
    #pragma unroll
    for (int ni = 0; ni < 2; ++ni) {
        const int col = c0 + wn + ni * 16 + l15;
        #pragma unroll
        for (int g = 0; g < 3; ++g) {
            bhh_[g][ni] = b_hh[col + g * SH];
            bih_[g][ni] = b_ih[col + g * SH];
            gr_[g][ni]  = g_raw[col + g * SH];
        }
    }
    #pragma unroll
    for (int mi = 0; mi < 4; ++mi) {
        #pragma unroll
        for (int j = 0; j < 4; ++j) {
            const int row = m0 + wm + mi * 16 + l4 * 4 + j;
            const float bt = beta[row];
            #pragma unroll
            for (int ni = 0; ni < 2; ++ni) {
                const int col = c0 + wn + ni * 16 + l15;
                const float hp = h32[(size_t)row * SH + col];
                const float ghr = acc[mi][0][ni][j] + bhh_[0][ni];
                const float ghz = acc[mi][1][ni][j] + bhh_[1][ni];
                const float ghn = acc[mi][2][ni][j] + bhh_[2][ni];
                const float gir = fmaf(bt, gr_[0][ni], bih_[0][ni]);
                const float giz = fmaf(bt, gr_[1][ni], bih_[1][ni]);
                const float gin = fmaf(bt, gr_[2][ni], bih_[2][ni]);
                const float r = sigmoid_fast(gir + ghr);
                const float z = sigmoid_fast(giz + ghz);
                const float n = tanh_fast(fmaf(r, ghn, gin));
                out[1 + (size_t)row * SH + col] = (1.0f - z) * n + z * hp;
            }
        }
    }
}

// ---------------------------------------------------------------------------
extern "C" void kernel_launch(void* const* d_in, const int* in_sizes, int n_in,
                              void* d_out, int out_size, void* d_ws, size_t ws_size,
                              hipStream_t stream) {
    const int*   topic     = (const int*)d_in[0];
    const float* knowledge = (const float*)d_in[1];
    const float* score     = (const float*)d_in[2];
    const float* emb       = (const float*)d_in[3];
    const float* Wih_f     = (const float*)d_in[4];
    const float* Whh_f     = (const float*)d_in[5];
    const float* bih_f     = (const float*)d_in[6];
    const float* bhh_f     = (const float*)d_in[7];
    const float* Wih_b     = (const float*)d_in[8];
    const float* Whh_b     = (const float*)d_in[9];
    const float* bih_b     = (const float*)d_in[10];
    const float* bhh_b     = (const float*)d_in[11];
    const float* Wk        = (const float*)d_in[12];
    const float* bk        = (const float*)d_in[13];
    const float* km        = (const float*)d_in[14];
    const float* h0        = (const float*)d_in[15];
    const float* Ws        = (const float*)d_in[16];
    const float* bs        = (const float*)d_in[17];
    const float* Wih_s     = (const float*)d_in[18];
    const float* Whh_s     = (const float*)d_in[19];
    const float* bih_s     = (const float*)d_in[20];
    const float* bhh_s     = (const float*)d_in[21];

    float* out = (float*)d_out;
    float* ws  = (float*)d_ws;

    // workspace layout (floats)
    float* v     = ws + 0;       // 256
    float* kn    = ws + 256;     // 64
    float* alpha = ws + 320;     // 16384
    float* beta  = ws + 16704;   // 16384
    float* part  = ws + 33088;   // 128*512
    float* x_in  = ws + 98624;   // 513 (pad 516)
    float* g_raw = ws + 99140;   // 1536
    float* gi_ws = ws + 100680;  // 2*64*384 (ends ~599KB)

    // fp16 region (16B-aligned)
    const size_t H16_OFF = 655360;                       // 640 KB
    const size_t W16_OFF = H16_OFF + (size_t)KCNT * SH * 2;  // +16 MB
    const size_t NEED    = W16_OFF + (size_t)GS3 * SH * 2;   // +1.5 MB
    _Float16* h16 = (_Float16*)((char*)d_ws + H16_OFF);
    _Float16* W16 = (_Float16*)((char*)d_ws + W16_OFF);

    cvt_f16_kernel<<<(KCNT * SH / 8 + 255) / 256, 256, 0, stream>>>(
        h0, h16, KCNT * SH / 8);
    cvt_f16_kernel<<<(GS3 * SH / 8 + 255) / 256, 256, 0, stream>>>(
        Whh_s, W16, GS3 * SH / 8);

    topic_gi_kernel<<<dim3(SEQ, 2), G3, 0, stream>>>(topic, emb, Wih_f, bih_f,
                                                     Wih_b, bih_b, gi_ws);
    topic_gru_seq_kernel<<<2, 512, 0, stream>>>(Whh_f, bhh_f, Whh_b, bhh_b,
                                                gi_ws, v);
    kn_kernel<<<KE, 256, 0, stream>>>(Wk, bk, knowledge, kn);
    alpha_kernel<<<KCNT * 64 / 256, 256, 0, stream>>>(km, kn, alpha);
    softmax_kernel<<<1, 1024, 0, stream>>>(alpha, beta);
    hkp_partial_kernel<<<128, 512, 0, stream>>>(beta, h16, part);
    score_xin_kernel<<<1, 512, 0, stream>>>(part, v, score, Ws, bs, x_in, out);
    gih_kernel<<<GS3 / 4, 256, 0, stream>>>(Wih_s, x_in, g_raw);

    slot_gru_mfma_kernel<<<(KCNT / 128) * (SH / 64), 256, 0, stream>>>(
        h0, h16, W16, beta, g_raw, bih_s, bhh_s, out);
}